// Round 4
// baseline (333.649 us; speedup 1.0000x reference)
//
#include <hip/hip_runtime.h>
#include <hip/hip_bf16.h>
#include <math.h>

#define B 8
#define CIN 12
#define CQ 36
#define CP 48               // channel dim padded for MFMA K (32 + 16)
#define N 4096
#define SCALE 0.28867513459481287f   // 1/sqrt(12)
#define LOG2E 1.4426950408889634f
#define ZSPLIT 8
#define NCHUNK (N / ZSPLIT) // 512
#define MS 4                // stats m-splits

typedef __attribute__((ext_vector_type(4)))  short bf4_t;   // 4 bf16 = 2 VGPRs
typedef __attribute__((ext_vector_type(8)))  short bf8_t;   // 8 bf16 = 4 VGPRs
typedef __attribute__((ext_vector_type(4)))  float f32x4;

__device__ __forceinline__ unsigned short f2bf(float x) {
  unsigned int u = __float_as_uint(x);
  u += 0x7FFFu + ((u >> 16) & 1u);   // round-to-nearest-even
  return (unsigned short)(u >> 16);
}

#if __has_builtin(__builtin_amdgcn_cvt_pk_bf16_f32)
typedef __attribute__((ext_vector_type(2))) __bf16 bf16x2_t;
__device__ __forceinline__ unsigned pk2bf(float a, float b) {
  bf16x2_t v = __builtin_amdgcn_cvt_pk_bf16_f32(a, b);
  return __builtin_bit_cast(unsigned, v);
}
#else
__device__ __forceinline__ unsigned pk2bf(float a, float b) {
  return (unsigned)f2bf(a) | ((unsigned)f2bf(b) << 16);
}
#endif

__device__ __forceinline__ float bf2f(unsigned short u) {
  return __uint_as_float((unsigned)u << 16);
}

__device__ __forceinline__ float exp2fast(float x) {
#if __has_builtin(__builtin_amdgcn_exp2f)
  return __builtin_amdgcn_exp2f(x);
#else
  return exp2f(x);
#endif
}

// 16x16x16 bf16 MFMA (quad-K layout: A[m=l15][k=q4*4+i], B[k=q4*4+i][n=l15],
// D col=l15 row=q4*4+r). Fallback emulates it with 16x16x32 + half-zero
// octets (identical lane mapping: real k quad q4*4+i -> virtual q4*8+i,
// upper half zero in BOTH operands).
__device__ __forceinline__ f32x4 mfma16(bf4_t a, bf4_t b, f32x4 c) {
#if __has_builtin(__builtin_amdgcn_mfma_f32_16x16x16bf16_1k)
  return __builtin_amdgcn_mfma_f32_16x16x16bf16_1k(a, b, c, 0, 0, 0);
#else
  bf8_t a8 = {a[0], a[1], a[2], a[3], 0, 0, 0, 0};
  bf8_t b8 = {b[0], b[1], b[2], b[3], 0, 0, 0, 0};
  return __builtin_amdgcn_mfma_f32_16x16x32_bf16(a8, b8, c, 0, 0, 0);
#endif
}

// ---------------- QKV projection: y-split over {q,k,v} ---------------------
// k gets SCALE*LOG2E folded in -> scores come out of MFMA in log2 domain.
__global__ __launch_bounds__(256) void qkv_kernel(
    const float* __restrict__ x,
    const float* __restrict__ wq, const float* __restrict__ bq,
    const float* __restrict__ wk, const float* __restrict__ bk,
    const float* __restrict__ wv, const float* __restrict__ bv,
    unsigned short* __restrict__ qT, unsigned short* __restrict__ kT,
    float* __restrict__ v) {
  __shared__ float sw[CQ * CIN];
  __shared__ float sb[CQ];
  int z = blockIdx.y;   // 0->q, 1->k (scaled), 2->v
  const float* w  = (z == 0) ? wq : (z == 1) ? wk : wv;
  const float* bb = (z == 0) ? bq : (z == 1) ? bk : bv;
  float scale = (z == 1) ? SCALE * LOG2E : 1.0f;
  int tid = threadIdx.x;
  for (int e = tid; e < CQ * CIN; e += 256) sw[e] = w[e] * scale;
  if (tid < CQ) sb[tid] = bb[tid] * scale;
  __syncthreads();
  int gid = blockIdx.x * 256 + tid;    // over B*N
  int b = gid >> 12;
  int n = gid & (N - 1);
  float xv[CIN];
#pragma unroll
  for (int i = 0; i < CIN; ++i) xv[i] = x[(b * CIN + i) * N + n];
  if (z == 2) {
#pragma unroll
    for (int o = 0; o < CQ; ++o) {
      float a = sb[o];
#pragma unroll
      for (int i = 0; i < CIN; ++i) a += sw[o * CIN + i] * xv[i];
      v[((size_t)b * CQ + o) * N + n] = a;
    }
  } else {
    __attribute__((aligned(16))) unsigned row[CP / 2];
#pragma unroll
    for (int o = 0; o < CQ; o += 2) {
      float a0 = sb[o], a1 = sb[o + 1];
#pragma unroll
      for (int i = 0; i < CIN; ++i) {
        float xi = xv[i];
        a0 += sw[o * CIN + i] * xi;
        a1 += sw[(o + 1) * CIN + i] * xi;
      }
      row[o / 2] = pk2bf(a0, a1);
    }
#pragma unroll
    for (int o = CQ / 2; o < CP / 2; ++o) row[o] = 0;
    unsigned short* dst = ((z == 0) ? qT : kT) + ((size_t)b * N + n) * CP;
#pragma unroll
    for (int i = 0; i < 6; ++i) *(uint4*)(dst + 8 * i) = *(const uint4*)&row[4 * i];
  }
}

// ---------------- Pass 1: psum[ms][b][n] = partial sum_m 2^(s[n,m]) --------
__global__ __launch_bounds__(256) void stats_kernel(
    const unsigned short* __restrict__ qT, const unsigned short* __restrict__ kT,
    float* __restrict__ psum) {
  int tid = threadIdx.x, lane = tid & 63, wave = tid >> 6;
  int l15 = lane & 15, q4 = lane >> 4;
  int b = blockIdx.y, ms = blockIdx.z;
  int n0 = (blockIdx.x * 4 + wave) * 16;
  const size_t bN = (size_t)b * N;
  // A frags (k rows, loop-invariant): A[n=l15][k quads]
  const unsigned short* krow = kT + (bN + n0 + l15) * CP;
  bf8_t ka32 = *(const bf8_t*)(krow + q4 * 8);
  bf4_t ka16 = *(const bf4_t*)(krow + 32 + q4 * 4);
  f32x4 rs = {0.f, 0.f, 0.f, 0.f};
  const unsigned short* qbase = qT + (bN + ms * (N / MS) + l15) * CP;
  for (int t = 0; t < (N / MS) / 32; ++t) {
    const unsigned short* qr0 = qbase + (size_t)t * 32 * CP;
    const unsigned short* qr1 = qr0 + 16 * CP;
    bf8_t qb32_0 = *(const bf8_t*)(qr0 + q4 * 8);
    bf4_t qb16_0 = *(const bf4_t*)(qr0 + 32 + q4 * 4);
    bf8_t qb32_1 = *(const bf8_t*)(qr1 + q4 * 8);
    bf4_t qb16_1 = *(const bf4_t*)(qr1 + 32 + q4 * 4);
    f32x4 S0 = {0.f, 0.f, 0.f, 0.f}, S1 = {0.f, 0.f, 0.f, 0.f};
    S0 = __builtin_amdgcn_mfma_f32_16x16x32_bf16(ka32, qb32_0, S0, 0, 0, 0);
    S0 = mfma16(ka16, qb16_0, S0);
    S1 = __builtin_amdgcn_mfma_f32_16x16x32_bf16(ka32, qb32_1, S1, 0, 0, 0);
    S1 = mfma16(ka16, qb16_1, S1);
#pragma unroll
    for (int r = 0; r < 4; ++r) rs[r] += exp2fast(S0[r]) + exp2fast(S1[r]);
  }
  // reduce over the 16-lane m-group (masks stay within a q4 group)
#pragma unroll
  for (int off = 8; off >= 1; off >>= 1)
#pragma unroll
    for (int r = 0; r < 4; ++r) rs[r] += __shfl_xor(rs[r], off);
  if (l15 == 0) {
#pragma unroll
    for (int r = 0; r < 4; ++r)
      psum[((size_t)ms * B + b) * N + n0 + q4 * 4 + r] = rs[r];
  }
}

// ---------------- vbf[b][c][n] = bf16(v * 1/rowsum[n]) (c-split) -----------
__global__ __launch_bounds__(256) void vscale_kernel(
    const float* __restrict__ v, const float* __restrict__ psum,
    unsigned short* __restrict__ vbf) {
  int gid = blockIdx.x * 256 + threadIdx.x;  // = b*N + n
  int b = gid >> 12;
  int n = gid & (N - 1);
  float s = 0.f;
#pragma unroll
  for (int ms = 0; ms < MS; ++ms) s += psum[(size_t)ms * B * N + gid];
  float r = 1.0f / s;
  int c0 = blockIdx.y * 12;
#pragma unroll
  for (int j = 0; j < 12; ++j) {
    int c = c0 + j;
    vbf[((size_t)b * CP + c) * N + n] = f2bf(v[((size_t)b * CQ + c) * N + n] * r);
  }
  // vbf rows 36..47 unwritten: those A-rows only feed unstored output rows.
}

// ---------------- Pass 2: pattn[z][c][m] (bf16), zero-LDS ------------------
__global__ __launch_bounds__(256) void attn_kernel(
    const unsigned short* __restrict__ qT, const unsigned short* __restrict__ kT,
    const unsigned short* __restrict__ vbf, unsigned short* __restrict__ pattn) {
  int tid = threadIdx.x, lane = tid & 63, wave = tid >> 6;
  int l15 = lane & 15, q4 = lane >> 4;
  int b = blockIdx.y, z = blockIdx.z;
  int m0 = (blockIdx.x * 4 + wave) * 16;
  const size_t bN = (size_t)b * N;
  // q B-frags (loop-invariant): B[k=c quads][m=l15]
  const unsigned short* qrow = qT + (bN + m0 + l15) * CP;
  bf8_t qb32 = *(const bf8_t*)(qrow + q4 * 8);
  bf4_t qb16 = *(const bf4_t*)(qrow + 32 + q4 * 4);
  f32x4 acc[3];
#pragma unroll
  for (int ct = 0; ct < 3; ++ct)
#pragma unroll
    for (int r = 0; r < 4; ++r) acc[ct][r] = 0.f;
  const unsigned short* kbase = kT + (bN + z * NCHUNK + l15) * CP;
  const unsigned short* vbase = vbf + (size_t)b * CP * N + z * NCHUNK + q4 * 4;
  for (int t = 0; t < NCHUNK / 32; ++t) {
    int n0 = t * 32;
    const unsigned short* kr0 = kbase + (size_t)n0 * CP;
    const unsigned short* kr1 = kr0 + 16 * CP;
    bf8_t ka32_0 = *(const bf8_t*)(kr0 + q4 * 8);
    bf4_t ka16_0 = *(const bf4_t*)(kr0 + 32 + q4 * 4);
    bf8_t ka32_1 = *(const bf8_t*)(kr1 + q4 * 8);
    bf4_t ka16_1 = *(const bf4_t*)(kr1 + 32 + q4 * 4);
    // S tiles: D[n = q4*4+r][m = l15], log2 domain
    f32x4 S0 = {0.f, 0.f, 0.f, 0.f}, S1 = {0.f, 0.f, 0.f, 0.f};
    S0 = __builtin_amdgcn_mfma_f32_16x16x32_bf16(ka32_0, qb32, S0, 0, 0, 0);
    S0 = mfma16(ka16_0, qb16, S0);
    S1 = __builtin_amdgcn_mfma_f32_16x16x32_bf16(ka32_1, qb32, S1, 0, 0, 0);
    S1 = mfma16(ka16_1, qb16, S1);
    // P = 2^S packed to bf16 quad: D layout == 16x16x16 B-operand layout.
    union { uint2 u; bf4_t v; } p0, p1;
    p0.u.x = pk2bf(exp2fast(S0[0]), exp2fast(S0[1]));
    p0.u.y = pk2bf(exp2fast(S0[2]), exp2fast(S0[3]));
    p1.u.x = pk2bf(exp2fast(S1[0]), exp2fast(S1[1]));
    p1.u.y = pk2bf(exp2fast(S1[2]), exp2fast(S1[3]));
    // PV: A = v' rows (c), k = n quads
    const unsigned short* vr = vbase + n0;
#pragma unroll
    for (int ct = 0; ct < 3; ++ct) {
      const unsigned short* vrc = vr + (size_t)(ct * 16 + l15) * N;
      bf4_t va0 = *(const bf4_t*)(vrc);
      bf4_t va1 = *(const bf4_t*)(vrc + 16);
      acc[ct] = mfma16(va0, p0.v, acc[ct]);
      acc[ct] = mfma16(va1, p1.v, acc[ct]);
    }
  }
#pragma unroll
  for (int ct = 0; ct < 3; ++ct)
#pragma unroll
    for (int r = 0; r < 4; ++r) {
      int c = ct * 16 + q4 * 4 + r;
      if (c < CQ)
        pattn[(((size_t)z * B + b) * CQ + c) * N + m0 + l15] = f2bf(acc[ct][r]);
    }
}

// ---------------- zero d_out (poisoned 0xAA by harness) --------------------
__global__ __launch_bounds__(256) void zero_kernel(float4* __restrict__ p) {
  p[blockIdx.x * 256 + threadIdx.x] = float4{0.f, 0.f, 0.f, 0.f};
}

// ---------------- sum z-splits + output projection (c-split x2) ------------
__global__ __launch_bounds__(256) void out_kernel(
    const unsigned short* __restrict__ pattn,
    const float* __restrict__ wo, const float* __restrict__ bo,
    float* __restrict__ out) {
  __shared__ float swo[CIN * CQ];
  __shared__ float sbo[CIN];
  int tid = threadIdx.x;
  for (int e = tid; e < CIN * CQ; e += 256) swo[e] = wo[e];
  if (tid < CIN) sbo[tid] = bo[tid];
  __syncthreads();
  int half = blockIdx.y;            // c in [half*18, half*18+18)
  int gid = blockIdx.x * 256 + tid;
  int b = gid >> 12;
  int m = gid & (N - 1);
  float at[18];
#pragma unroll
  for (int j = 0; j < 18; ++j) {
    int c = half * 18 + j;
    float s = 0.f;
#pragma unroll
    for (int z = 0; z < ZSPLIT; ++z)
      s += bf2f(pattn[(((size_t)z * B + b) * CQ + c) * N + m]);
    at[j] = s;
  }
#pragma unroll
  for (int i = 0; i < CIN; ++i) {
    float o = (half == 0) ? sbo[i] : 0.f;
#pragma unroll
    for (int j = 0; j < 18; ++j) o += swo[i * CQ + half * 18 + j] * at[j];
    atomicAdd(&out[((size_t)b * CIN + i) * N + m], o);
  }
}

extern "C" void kernel_launch(void* const* d_in, const int* in_sizes, int n_in,
                              void* d_out, int out_size, void* d_ws, size_t ws_size,
                              hipStream_t stream) {
  const float* x  = (const float*)d_in[0];
  const float* wq = (const float*)d_in[1];
  const float* bq = (const float*)d_in[2];
  const float* wk = (const float*)d_in[3];
  const float* bk = (const float*)d_in[4];
  const float* wv = (const float*)d_in[5];
  const float* bv = (const float*)d_in[6];
  const float* wo = (const float*)d_in[7];
  const float* bo = (const float*)d_in[8];
  float* out = (float*)d_out;

  char* ws = (char*)d_ws;
  unsigned short* qT  = (unsigned short*)ws;                        // 3,145,728 B
  unsigned short* kT  = (unsigned short*)(ws + 3145728);            // 3,145,728 B
  unsigned short* vbf = (unsigned short*)(ws + 2 * 3145728);        // 3,145,728 B
  float* v    = (float*)(ws + 3 * 3145728);                         // 4,718,592 B
  float* psum = (float*)(ws + 3 * 3145728 + 4718592);               //   524,288 B
  unsigned short* pattn =
      (unsigned short*)(ws + 3 * 3145728 + 4718592 + 524288);       // 18,874,368 B

  qkv_kernel<<<dim3(B * N / 256, 3), 256, 0, stream>>>(x, wq, bq, wk, bk, wv, bv,
                                                       qT, kT, v);
  stats_kernel<<<dim3(N / 64, B, MS), 256, 0, stream>>>(qT, kT, psum);
  vscale_kernel<<<dim3(B * N / 256, 3), 256, 0, stream>>>(v, psum, vbf);
  attn_kernel<<<dim3(N / 64, B, ZSPLIT), 256, 0, stream>>>(qT, kT, vbf, pattn);
  zero_kernel<<<B * CIN * N / 1024, 256, 0, stream>>>((float4*)out);
  out_kernel<<<dim3(B * N / 256, 2), 256, 0, stream>>>(pattn, wo, bo, out);
}

// Round 5
// 238.031 us; speedup vs baseline: 1.4017x; 1.4017x over previous
//
#include <hip/hip_runtime.h>
#include <hip/hip_bf16.h>

#define B 8
#define CIN 12
#define CQ 36
#define CP 48               // channel dim padded for MFMA K (3x16)
#define N 4096
#define SCALE 0.28867513459481287f   // 1/sqrt(12)
#define LOG2E 1.4426950408889634f
#define ZSPLIT 8
#define NCHUNK (N / ZSPLIT) // 512
#define MSPLIT 2

typedef __attribute__((ext_vector_type(8)))  short bf8_t;   // 8 bf16 = 4 VGPRs
typedef __attribute__((ext_vector_type(16))) float f32x16;
typedef __attribute__((ext_vector_type(4)))  float f32x4;

__device__ __forceinline__ unsigned short f2bf(float x) {
  unsigned int u = __float_as_uint(x);
  u += 0x7FFFu + ((u >> 16) & 1u);   // round-to-nearest-even
  return (unsigned short)(u >> 16);
}

#if __has_builtin(__builtin_amdgcn_cvt_pk_bf16_f32)
typedef __attribute__((ext_vector_type(2))) __bf16 bf16x2_t;
__device__ __forceinline__ unsigned pk2bf(float a, float b) {
  bf16x2_t v = __builtin_amdgcn_cvt_pk_bf16_f32(a, b);
  return __builtin_bit_cast(unsigned, v);
}
#else
// truncating pack (P is non-negative; bias < 2^-8 rel, threshold has 6x room)
__device__ __forceinline__ unsigned pk2bf(float a, float b) {
  return (__float_as_uint(a) >> 16) | (__float_as_uint(b) & 0xFFFF0000u);
}
#endif

__device__ __forceinline__ float bf2f(unsigned short u) {
  return __uint_as_float((unsigned)u << 16);
}

__device__ __forceinline__ float exp2fast(float x) {
#if __has_builtin(__builtin_amdgcn_exp2f)
  return __builtin_amdgcn_exp2f(x);
#else
  return exp2f(x);
#endif
}

// ---------------- QKV projection: y-split over {q,k,v} ---------------------
// k gets SCALE*LOG2E folded in -> MFMA scores are already log2-domain.
__global__ __launch_bounds__(256) void qkv_kernel(
    const float* __restrict__ x,
    const float* __restrict__ wq, const float* __restrict__ bq,
    const float* __restrict__ wk, const float* __restrict__ bk,
    const float* __restrict__ wv, const float* __restrict__ bv,
    unsigned short* __restrict__ qT, unsigned short* __restrict__ kT,
    float* __restrict__ v) {
  __shared__ float sw[CQ * CIN];
  __shared__ float sb[CQ];
  int z = blockIdx.y;   // 0->q, 1->k (scaled), 2->v
  const float* w  = (z == 0) ? wq : (z == 1) ? wk : wv;
  const float* bb = (z == 0) ? bq : (z == 1) ? bk : bv;
  float scale = (z == 1) ? SCALE * LOG2E : 1.0f;
  int tid = threadIdx.x;
  for (int e = tid; e < CQ * CIN; e += 256) sw[e] = w[e] * scale;
  if (tid < CQ) sb[tid] = bb[tid] * scale;
  __syncthreads();
  int gid = blockIdx.x * 256 + tid;    // over B*N
  int b = gid >> 12;
  int n = gid & (N - 1);
  float xv[CIN];
#pragma unroll
  for (int i = 0; i < CIN; ++i) xv[i] = x[(b * CIN + i) * N + n];
  if (z == 2) {
#pragma unroll
    for (int o = 0; o < CQ; ++o) {
      float a = sb[o];
#pragma unroll
      for (int i = 0; i < CIN; ++i) a += sw[o * CIN + i] * xv[i];
      v[((size_t)b * CQ + o) * N + n] = a;
    }
  } else {
    __attribute__((aligned(16))) unsigned row[CP / 2];
#pragma unroll
    for (int o = 0; o < CQ; o += 2) {
      float a0 = sb[o], a1 = sb[o + 1];
#pragma unroll
      for (int i = 0; i < CIN; ++i) {
        float xi = xv[i];
        a0 += sw[o * CIN + i] * xi;
        a1 += sw[(o + 1) * CIN + i] * xi;
      }
      row[o / 2] = (unsigned)f2bf(a0) | ((unsigned)f2bf(a1) << 16);
    }
#pragma unroll
    for (int o = CQ / 2; o < CP / 2; ++o) row[o] = 0;
    unsigned short* dst = ((z == 0) ? qT : kT) + ((size_t)b * N + n) * CP;
#pragma unroll
    for (int i = 0; i < 6; ++i) *(uint4*)(dst + 8 * i) = *(const uint4*)&row[4 * i];
  }
}

// ---------------- Pass 1: psum[z][b][n] = partial sum_m 2^(s[n,m]) ---------
__global__ __launch_bounds__(256) void stats_kernel(
    const unsigned short* __restrict__ qT, const unsigned short* __restrict__ kT,
    float* __restrict__ psum) {
  __shared__ float red[4][32];
  int tid = threadIdx.x, lane = tid & 63, wave = tid >> 6;
  int b = blockIdx.y, nblk = blockIdx.x, z = blockIdx.z;
  int l31 = lane & 31, h = lane >> 5;
  const unsigned short* krow = kT + ((size_t)b * N + nblk * 32 + l31) * CP + h * 8;
  bf8_t a0 = *(const bf8_t*)(krow);
  bf8_t a1 = *(const bf8_t*)(krow + 16);
  bf8_t a2 = *(const bf8_t*)(krow + 32);
  float rs[16];
#pragma unroll
  for (int r = 0; r < 16; ++r) rs[r] = 0.f;
  const int MW = N / MSPLIT / 4;   // 512 m per wave
  const unsigned short* qbase =
      qT + ((size_t)b * N + z * (N / MSPLIT) + wave * MW + l31) * CP + h * 8;
#pragma unroll 2
  for (int t = 0; t < MW / 32; ++t) {
    const unsigned short* qrow2 = qbase + (size_t)t * 32 * CP;
    bf8_t b0 = *(const bf8_t*)(qrow2);
    bf8_t b1 = *(const bf8_t*)(qrow2 + 16);
    bf8_t b2 = *(const bf8_t*)(qrow2 + 32);
    f32x16 S;
#pragma unroll
    for (int r = 0; r < 16; ++r) S[r] = 0.f;
    S = __builtin_amdgcn_mfma_f32_32x32x16_bf16(a0, b0, S, 0, 0, 0);
    S = __builtin_amdgcn_mfma_f32_32x32x16_bf16(a1, b1, S, 0, 0, 0);
    S = __builtin_amdgcn_mfma_f32_32x32x16_bf16(a2, b2, S, 0, 0, 0);
#pragma unroll
    for (int r = 0; r < 16; ++r) rs[r] += exp2fast(S[r]);
  }
#pragma unroll
  for (int off = 16; off >= 1; off >>= 1)
#pragma unroll
    for (int r = 0; r < 16; ++r) rs[r] += __shfl_xor(rs[r], off, 32);
  if (l31 == 0) {
#pragma unroll
    for (int r = 0; r < 16; ++r) {
      int row = (r & 3) + 8 * (r >> 2) + 4 * h;   // 32x32 C/D row map
      red[wave][row] = rs[r];
    }
  }
  __syncthreads();
  if (tid < 32) {
    float s = red[0][tid] + red[1][tid] + red[2][tid] + red[3][tid];
    psum[((size_t)z * B + b) * N + nblk * 32 + tid] = s;
  }
}

// ---------------- vbf[b][c][n] = bf16(v * 1/rowsum[n]) (c-split) -----------
__global__ __launch_bounds__(256) void vscale_kernel(
    const float* __restrict__ v, const float* __restrict__ psum,
    unsigned short* __restrict__ vbf) {
  int gid = blockIdx.x * 256 + threadIdx.x;  // = b*N + n
  int b = gid >> 12;
  int n = gid & (N - 1);
  float r = 1.0f / (psum[gid] + psum[(size_t)B * N + gid]);
  int c0 = blockIdx.y * 12;
#pragma unroll
  for (int j = 0; j < 12; ++j) {
    int c = c0 + j;
    vbf[((size_t)b * CP + c) * N + n] = f2bf(v[((size_t)b * CQ + c) * N + n] * r);
  }
  // vbf rows 36..47 unwritten: those A-rows only feed unstored output rows.
}

// ---------------- Pass 2: pattn[z][c][m] (bf16) ----------------------------
__global__ __launch_bounds__(256, 4) void attn_kernel(
    const unsigned short* __restrict__ qT, const unsigned short* __restrict__ kT,
    const unsigned short* __restrict__ vbf, unsigned short* __restrict__ pattn) {
  __shared__ unsigned short plds[4][2][32 * 40];  // per-wave dbuf P^T [m][n pad40]
  int tid = threadIdx.x, lane = tid & 63, wave = tid >> 6;
  int b = blockIdx.y, z = blockIdx.z, mblk = blockIdx.x;
  int l31 = lane & 31, h = lane >> 5, l15 = lane & 15, q4 = lane >> 4;
  int m0 = mblk * 128 + wave * 32;
  const unsigned short* qrow = qT + ((size_t)b * N + m0 + l31) * CP + h * 8;
  bf8_t qb0 = *(const bf8_t*)(qrow);
  bf8_t qb1 = *(const bf8_t*)(qrow + 16);
  bf8_t qb2 = *(const bf8_t*)(qrow + 32);
  f32x4 acc[3][2];
#pragma unroll
  for (int ct = 0; ct < 3; ++ct)
#pragma unroll
    for (int hm = 0; hm < 2; ++hm)
#pragma unroll
      for (int r = 0; r < 4; ++r) acc[ct][hm][r] = 0.f;
  const unsigned short* kbase = kT + ((size_t)b * N + z * NCHUNK + l31) * CP + h * 8;
  const unsigned short* vbase = vbf + (size_t)b * CP * N + z * NCHUNK + q4 * 8;
#pragma unroll 2
  for (int t = 0; t < NCHUNK / 32; ++t) {
    unsigned short* pl = plds[wave][t & 1];
    const unsigned short* krow = kbase + (size_t)t * 32 * CP;
    bf8_t a0 = *(const bf8_t*)(krow);
    bf8_t a1 = *(const bf8_t*)(krow + 16);
    bf8_t a2 = *(const bf8_t*)(krow + 32);
    f32x16 S;
#pragma unroll
    for (int r = 0; r < 16; ++r) S[r] = 0.f;
    S = __builtin_amdgcn_mfma_f32_32x32x16_bf16(a0, qb0, S, 0, 0, 0);
    S = __builtin_amdgcn_mfma_f32_32x32x16_bf16(a1, qb1, S, 0, 0, 0);
    S = __builtin_amdgcn_mfma_f32_32x32x16_bf16(a2, qb2, S, 0, 0, 0);
    // P = 2^S -> bf16, store transposed [m][n] (rows 8qd+4h+0..3 contiguous)
#pragma unroll
    for (int qd = 0; qd < 4; ++qd) {
      uint2 pk;
      pk.x = pk2bf(exp2fast(S[4 * qd + 0]), exp2fast(S[4 * qd + 1]));
      pk.y = pk2bf(exp2fast(S[4 * qd + 2]), exp2fast(S[4 * qd + 3]));
      *(uint2*)&pl[l31 * 40 + 8 * qd + 4 * h] = pk;
    }
    bf8_t pb0 = *(const bf8_t*)&pl[l15 * 40 + q4 * 8];
    bf8_t pb1 = *(const bf8_t*)&pl[(16 + l15) * 40 + q4 * 8];
    const unsigned short* vrow = vbase + (size_t)t * 32;
    bf8_t v0 = *(const bf8_t*)(vrow + (size_t)(0 * 16 + l15) * N);
    bf8_t v1 = *(const bf8_t*)(vrow + (size_t)(1 * 16 + l15) * N);
    bf8_t v2 = *(const bf8_t*)(vrow + (size_t)(2 * 16 + l15) * N);
    acc[0][0] = __builtin_amdgcn_mfma_f32_16x16x32_bf16(v0, pb0, acc[0][0], 0, 0, 0);
    acc[0][1] = __builtin_amdgcn_mfma_f32_16x16x32_bf16(v0, pb1, acc[0][1], 0, 0, 0);
    acc[1][0] = __builtin_amdgcn_mfma_f32_16x16x32_bf16(v1, pb0, acc[1][0], 0, 0, 0);
    acc[1][1] = __builtin_amdgcn_mfma_f32_16x16x32_bf16(v1, pb1, acc[1][1], 0, 0, 0);
    acc[2][0] = __builtin_amdgcn_mfma_f32_16x16x32_bf16(v2, pb0, acc[2][0], 0, 0, 0);
    acc[2][1] = __builtin_amdgcn_mfma_f32_16x16x32_bf16(v2, pb1, acc[2][1], 0, 0, 0);
  }
#pragma unroll
  for (int ct = 0; ct < 3; ++ct)
#pragma unroll
    for (int hm = 0; hm < 2; ++hm)
#pragma unroll
      for (int r = 0; r < 4; ++r) {
        int c = ct * 16 + q4 * 4 + r;
        if (c < CQ)
          pattn[(((size_t)z * B + b) * CQ + c) * N + m0 + hm * 16 + l15] =
              f2bf(acc[ct][hm][r]);
      }
}

// ---------------- sum z-splits + output projection (no atomics) ------------
__global__ __launch_bounds__(256) void out_kernel(
    const unsigned short* __restrict__ pattn,
    const float* __restrict__ wo, const float* __restrict__ bo,
    float* __restrict__ out) {
  __shared__ float swo[CIN * CQ];
  __shared__ float sbo[CIN];
  int tid = threadIdx.x;
  for (int e = tid; e < CIN * CQ; e += 256) swo[e] = wo[e];
  if (tid < CIN) sbo[tid] = bo[tid];
  __syncthreads();
  int gid = blockIdx.x * 256 + tid;
  int b = gid >> 12;
  int m = gid & (N - 1);
  float at[CQ];
#pragma unroll
  for (int c = 0; c < CQ; ++c) {
    float s = 0.f;
#pragma unroll
    for (int z = 0; z < ZSPLIT; ++z)
      s += bf2f(pattn[(((size_t)z * B + b) * CQ + c) * N + m]);
    at[c] = s;
  }
#pragma unroll
  for (int i = 0; i < CIN; ++i) {
    float o = sbo[i];
#pragma unroll
    for (int c = 0; c < CQ; ++c) o += swo[i * CQ + c] * at[c];
    out[((size_t)b * CIN + i) * N + m] = o;
  }
}

extern "C" void kernel_launch(void* const* d_in, const int* in_sizes, int n_in,
                              void* d_out, int out_size, void* d_ws, size_t ws_size,
                              hipStream_t stream) {
  const float* x  = (const float*)d_in[0];
  const float* wq = (const float*)d_in[1];
  const float* bq = (const float*)d_in[2];
  const float* wk = (const float*)d_in[3];
  const float* bk = (const float*)d_in[4];
  const float* wv = (const float*)d_in[5];
  const float* bv = (const float*)d_in[6];
  const float* wo = (const float*)d_in[7];
  const float* bo = (const float*)d_in[8];
  float* out = (float*)d_out;

  char* ws = (char*)d_ws;
  unsigned short* qT  = (unsigned short*)ws;                        // 3,145,728 B
  unsigned short* kT  = (unsigned short*)(ws + 3145728);            // 3,145,728 B
  unsigned short* vbf = (unsigned short*)(ws + 2 * 3145728);        // 3,145,728 B
  float* v    = (float*)(ws + 3 * 3145728);                         // 4,718,592 B
  float* psum = (float*)(ws + 3 * 3145728 + 4718592);               //   262,144 B
  unsigned short* pattn =
      (unsigned short*)(ws + 3 * 3145728 + 4718592 + 262144);       // 18,874,368 B

  qkv_kernel<<<dim3(B * N / 256, 3), 256, 0, stream>>>(x, wq, bq, wk, bk, wv, bv,
                                                       qT, kT, v);
  stats_kernel<<<dim3(N / 32, B, MSPLIT), 256, 0, stream>>>(qT, kT, psum);
  vscale_kernel<<<dim3(B * N / 256, 3), 256, 0, stream>>>(v, psum, vbf);
  attn_kernel<<<dim3(N / 128, B, ZSPLIT), 256, 0, stream>>>(qT, kT, vbf, pattn);
  out_kernel<<<B * N / 256, 256, 0, stream>>>(pattn, wo, bo, out);
}

// Round 6
// 171.273 us; speedup vs baseline: 1.9481x; 1.3898x over previous
//
#include <hip/hip_runtime.h>
#include <hip/hip_bf16.h>
#include <math.h>

#define B 8
#define CIN 12
#define CQ 36
#define CP 48               // channel dim padded for MFMA K (3x16)
#define N 4096
#define SCALE 0.28867513459481287f   // 1/sqrt(12)
#define LOG2E 1.4426950408889634f
#define ZSPLIT 4
#define NCHUNK (N / ZSPLIT) // 1024
#define MSPLIT 4

typedef __attribute__((ext_vector_type(4)))  short bf4_t;   // 4 bf16 = 2 VGPRs
typedef __attribute__((ext_vector_type(8)))  short bf8_t;   // 8 bf16 = 4 VGPRs
typedef __attribute__((ext_vector_type(16))) float f32x16;
typedef __attribute__((ext_vector_type(4)))  float f32x4;

__device__ __forceinline__ unsigned short f2bf(float x) {
  unsigned int u = __float_as_uint(x);
  u += 0x7FFFu + ((u >> 16) & 1u);   // round-to-nearest-even
  return (unsigned short)(u >> 16);
}

#if __has_builtin(__builtin_amdgcn_cvt_pk_bf16_f32)
typedef __attribute__((ext_vector_type(2))) __bf16 bf16x2_t;
__device__ __forceinline__ unsigned pk2bf(float a, float b) {
  bf16x2_t v = __builtin_amdgcn_cvt_pk_bf16_f32(a, b);
  return __builtin_bit_cast(unsigned, v);
}
#else
// truncating pack (bias < 2^-9 rel; threshold has ample room)
__device__ __forceinline__ unsigned pk2bf(float a, float b) {
  return (__float_as_uint(a) >> 16) | (__float_as_uint(b) & 0xFFFF0000u);
}
#endif

__device__ __forceinline__ float exp2fast(float x) {
#if __has_builtin(__builtin_amdgcn_exp2f)
  return __builtin_amdgcn_exp2f(x);
#else
  return exp2f(x);
#endif
}

// 16x16x16 bf16 MFMA, quad-K layout: A[m=l15][k=q4*4+i], B[k=q4*4+i][n=l15],
// D col=l15 row=q4*4+r (layout verified end-to-end in R4 run).
__device__ __forceinline__ f32x4 mfma16(bf4_t a, bf4_t b, f32x4 c) {
#if __has_builtin(__builtin_amdgcn_mfma_f32_16x16x16bf16_1k)
  return __builtin_amdgcn_mfma_f32_16x16x16bf16_1k(a, b, c, 0, 0, 0);
#else
  bf8_t a8 = {a[0], a[1], a[2], a[3], 0, 0, 0, 0};
  bf8_t b8 = {b[0], b[1], b[2], b[3], 0, 0, 0, 0};
  return __builtin_amdgcn_mfma_f32_16x16x32_bf16(a8, b8, c, 0, 0, 0);
#endif
}

// ---------------- QKV projection: y-split over {q,k,v} ---------------------
// k gets SCALE*LOG2E folded in -> MFMA scores are already log2-domain.
__global__ __launch_bounds__(256) void qkv_kernel(
    const float* __restrict__ x,
    const float* __restrict__ wq, const float* __restrict__ bq,
    const float* __restrict__ wk, const float* __restrict__ bk,
    const float* __restrict__ wv, const float* __restrict__ bv,
    unsigned short* __restrict__ qT, unsigned short* __restrict__ kT,
    float* __restrict__ v) {
  __shared__ float sw[CQ * CIN];
  __shared__ float sb[CQ];
  int z = blockIdx.y;   // 0->q, 1->k (scaled), 2->v
  const float* w  = (z == 0) ? wq : (z == 1) ? wk : wv;
  const float* bb = (z == 0) ? bq : (z == 1) ? bk : bv;
  float scale = (z == 1) ? SCALE * LOG2E : 1.0f;
  int tid = threadIdx.x;
  for (int e = tid; e < CQ * CIN; e += 256) sw[e] = w[e] * scale;
  if (tid < CQ) sb[tid] = bb[tid] * scale;
  __syncthreads();
  int gid = blockIdx.x * 256 + tid;    // over B*N
  int b = gid >> 12;
  int n = gid & (N - 1);
  float xv[CIN];
#pragma unroll
  for (int i = 0; i < CIN; ++i) xv[i] = x[(b * CIN + i) * N + n];
  if (z == 2) {
#pragma unroll
    for (int o = 0; o < CQ; ++o) {
      float a = sb[o];
#pragma unroll
      for (int i = 0; i < CIN; ++i) a += sw[o * CIN + i] * xv[i];
      v[((size_t)b * CQ + o) * N + n] = a;
    }
  } else {
    __attribute__((aligned(16))) unsigned row[CP / 2];
#pragma unroll
    for (int o = 0; o < CQ; o += 2) {
      float a0 = sb[o], a1 = sb[o + 1];
#pragma unroll
      for (int i = 0; i < CIN; ++i) {
        float xi = xv[i];
        a0 += sw[o * CIN + i] * xi;
        a1 += sw[(o + 1) * CIN + i] * xi;
      }
      row[o / 2] = (unsigned)f2bf(a0) | ((unsigned)f2bf(a1) << 16);
    }
#pragma unroll
    for (int o = CQ / 2; o < CP / 2; ++o) row[o] = 0;
    unsigned short* dst = ((z == 0) ? qT : kT) + ((size_t)b * N + n) * CP;
#pragma unroll
    for (int i = 0; i < 6; ++i) *(uint4*)(dst + 8 * i) = *(const uint4*)&row[4 * i];
  }
}

// ---------------- Pass 1: psum[ms][b][n] = partial sum_m 2^(s[n,m]) --------
__global__ __launch_bounds__(256) void stats_kernel(
    const unsigned short* __restrict__ qT, const unsigned short* __restrict__ kT,
    float* __restrict__ psum) {
  __shared__ float red[4][32];
  int tid = threadIdx.x, lane = tid & 63, wave = tid >> 6;
  int b = blockIdx.y, nblk = blockIdx.x, ms = blockIdx.z;
  int l31 = lane & 31, h = lane >> 5;
  const unsigned short* krow = kT + ((size_t)b * N + nblk * 32 + l31) * CP + h * 8;
  bf8_t a0 = *(const bf8_t*)(krow);
  bf8_t a1 = *(const bf8_t*)(krow + 16);
  bf8_t a2 = *(const bf8_t*)(krow + 32);
  float rs[16];
#pragma unroll
  for (int r = 0; r < 16; ++r) rs[r] = 0.f;
  const int MW = N / MSPLIT / 4;   // 256 m per wave
  const unsigned short* qbase =
      qT + ((size_t)b * N + ms * (N / MSPLIT) + wave * MW + l31) * CP + h * 8;
#pragma unroll 2
  for (int t = 0; t < MW / 32; ++t) {
    const unsigned short* qrow2 = qbase + (size_t)t * 32 * CP;
    bf8_t b0 = *(const bf8_t*)(qrow2);
    bf8_t b1 = *(const bf8_t*)(qrow2 + 16);
    bf8_t b2 = *(const bf8_t*)(qrow2 + 32);
    f32x16 S;
#pragma unroll
    for (int r = 0; r < 16; ++r) S[r] = 0.f;
    S = __builtin_amdgcn_mfma_f32_32x32x16_bf16(a0, b0, S, 0, 0, 0);
    S = __builtin_amdgcn_mfma_f32_32x32x16_bf16(a1, b1, S, 0, 0, 0);
    S = __builtin_amdgcn_mfma_f32_32x32x16_bf16(a2, b2, S, 0, 0, 0);
#pragma unroll
    for (int r = 0; r < 16; ++r) rs[r] += exp2fast(S[r]);
  }
#pragma unroll
  for (int off = 16; off >= 1; off >>= 1)
#pragma unroll
    for (int r = 0; r < 16; ++r) rs[r] += __shfl_xor(rs[r], off, 32);
  if (l31 == 0) {
#pragma unroll
    for (int r = 0; r < 16; ++r) {
      int row = (r & 3) + 8 * (r >> 2) + 4 * h;   // 32x32 C/D row map
      red[wave][row] = rs[r];
    }
  }
  __syncthreads();
  if (tid < 32) {
    float s = red[0][tid] + red[1][tid] + red[2][tid] + red[3][tid];
    psum[((size_t)ms * B + b) * N + nblk * 32 + tid] = s;
  }
}

// ---------------- vbf[b][c][n] = bf16(v * 1/rowsum[n]) (c-split) -----------
__global__ __launch_bounds__(256) void vscale_kernel(
    const float* __restrict__ v, const float* __restrict__ psum,
    unsigned short* __restrict__ vbf) {
  int gid = blockIdx.x * 256 + threadIdx.x;  // = b*N + n
  int b = gid >> 12;
  int n = gid & (N - 1);
  float s = 0.f;
#pragma unroll
  for (int ms = 0; ms < MSPLIT; ++ms) s += psum[(size_t)ms * B * N + gid];
  float r = 1.0f / s;
  int c0 = blockIdx.y * 12;
#pragma unroll
  for (int j = 0; j < 12; ++j) {
    int c = c0 + j;
    vbf[((size_t)b * CP + c) * N + n] = f2bf(v[((size_t)b * CQ + c) * N + n] * r);
  }
  // vbf rows 36..47 unwritten: those A-rows only feed unstored output rows.
}

// ---------------- init out with bias (out accumulated atomically) ----------
__global__ __launch_bounds__(256) void init_kernel(
    float* __restrict__ out, const float* __restrict__ bo) {
  int gid = blockIdx.x * 256 + threadIdx.x;   // over B*CIN*N/4
  int e4 = gid * 4;
  int i = (e4 >> 12) % CIN;
  float bv = bo[i];
  *(float4*)(out + e4) = float4{bv, bv, bv, bv};
}

// ---------------- Pass 2: fused attn + output projection -------------------
__global__ __launch_bounds__(256) void attn_kernel(
    const unsigned short* __restrict__ qT, const unsigned short* __restrict__ kT,
    const unsigned short* __restrict__ vbf, const float* __restrict__ wo,
    float* __restrict__ out) {
  __shared__ unsigned short plds[4][32 * 40];   // per-wave P^T tile [m][n pad40]
  int tid = threadIdx.x, lane = tid & 63, wave = tid >> 6;
  int b = blockIdx.y, z = blockIdx.z, mblk = blockIdx.x;
  int l31 = lane & 31, h = lane >> 5, l15 = lane & 15, q4 = lane >> 4;
  int m0 = mblk * 128 + wave * 32;
  const unsigned short* qrow = qT + ((size_t)b * N + m0 + l31) * CP + h * 8;
  bf8_t qb0 = *(const bf8_t*)(qrow);
  bf8_t qb1 = *(const bf8_t*)(qrow + 16);
  bf8_t qb2 = *(const bf8_t*)(qrow + 32);
  // wo A-frags for the fused projection: A[i=l15][k=16ct+q4*4+j] (rows >=12,
  // cols >=36 zero). wo rows are 144 B so every float4 here is 16B-aligned.
  bf4_t woa[3];
#pragma unroll
  for (int ct = 0; ct < 3; ++ct) {
    float4 w4 = {0.f, 0.f, 0.f, 0.f};
    int col = 16 * ct + q4 * 4;
    if (l15 < CIN && col < CQ) w4 = *(const float4*)(wo + l15 * CQ + col);
    woa[ct] = bf4_t{(short)f2bf(w4.x), (short)f2bf(w4.y),
                    (short)f2bf(w4.z), (short)f2bf(w4.w)};
  }
  f32x4 acc[3][2];
#pragma unroll
  for (int ct = 0; ct < 3; ++ct)
#pragma unroll
    for (int hm = 0; hm < 2; ++hm)
#pragma unroll
      for (int r = 0; r < 4; ++r) acc[ct][hm][r] = 0.f;
  unsigned short* pl = plds[wave];
  const unsigned short* kbase = kT + ((size_t)b * N + z * NCHUNK + l31) * CP + h * 8;
  const unsigned short* vbase = vbf + (size_t)b * CP * N + z * NCHUNK + q4 * 8;
  for (int t = 0; t < NCHUNK / 32; ++t) {
    const unsigned short* krow = kbase + (size_t)t * 32 * CP;
    bf8_t a0 = *(const bf8_t*)(krow);
    bf8_t a1 = *(const bf8_t*)(krow + 16);
    bf8_t a2 = *(const bf8_t*)(krow + 32);
    f32x16 S;
#pragma unroll
    for (int r = 0; r < 16; ++r) S[r] = 0.f;
    S = __builtin_amdgcn_mfma_f32_32x32x16_bf16(a0, qb0, S, 0, 0, 0);
    S = __builtin_amdgcn_mfma_f32_32x32x16_bf16(a1, qb1, S, 0, 0, 0);
    S = __builtin_amdgcn_mfma_f32_32x32x16_bf16(a2, qb2, S, 0, 0, 0);
    // P = 2^S -> bf16, store transposed [m][n] (rows 8qd+4h+0..3 contiguous)
#pragma unroll
    for (int qd = 0; qd < 4; ++qd) {
      uint2 pk;
      pk.x = pk2bf(exp2fast(S[4 * qd + 0]), exp2fast(S[4 * qd + 1]));
      pk.y = pk2bf(exp2fast(S[4 * qd + 2]), exp2fast(S[4 * qd + 3]));
      *(uint2*)&pl[l31 * 40 + 8 * qd + 4 * h] = pk;
    }
    bf8_t pb0 = *(const bf8_t*)&pl[l15 * 40 + q4 * 8];
    bf8_t pb1 = *(const bf8_t*)&pl[(16 + l15) * 40 + q4 * 8];
    const unsigned short* vrow = vbase + (size_t)t * 32;
    bf8_t v0 = *(const bf8_t*)(vrow + (size_t)(0 * 16 + l15) * N);
    bf8_t v1 = *(const bf8_t*)(vrow + (size_t)(1 * 16 + l15) * N);
    bf8_t v2 = *(const bf8_t*)(vrow + (size_t)(2 * 16 + l15) * N);
    acc[0][0] = __builtin_amdgcn_mfma_f32_16x16x32_bf16(v0, pb0, acc[0][0], 0, 0, 0);
    acc[0][1] = __builtin_amdgcn_mfma_f32_16x16x32_bf16(v0, pb1, acc[0][1], 0, 0, 0);
    acc[1][0] = __builtin_amdgcn_mfma_f32_16x16x32_bf16(v1, pb0, acc[1][0], 0, 0, 0);
    acc[1][1] = __builtin_amdgcn_mfma_f32_16x16x32_bf16(v1, pb1, acc[1][1], 0, 0, 0);
    acc[2][0] = __builtin_amdgcn_mfma_f32_16x16x32_bf16(v2, pb0, acc[2][0], 0, 0, 0);
    acc[2][1] = __builtin_amdgcn_mfma_f32_16x16x32_bf16(v2, pb1, acc[2][1], 0, 0, 0);
  }
  // Fused projection: attn tile (C-layout) == B-operand (quad-K) layout.
  // po[i=q4*4+r][m=l15] = sum_c wo[i][c] * attn[c][m]; atomic-accumulate over z.
#pragma unroll
  for (int hm = 0; hm < 2; ++hm) {
    f32x4 po = {0.f, 0.f, 0.f, 0.f};
#pragma unroll
    for (int ct = 0; ct < 3; ++ct) {
      union { uint2 u; bf4_t v; } pb;
      pb.u.x = pk2bf(acc[ct][hm][0], acc[ct][hm][1]);
      pb.u.y = pk2bf(acc[ct][hm][2], acc[ct][hm][3]);
      po = mfma16(woa[ct], pb.v, po);
    }
    if (q4 < 3) {
      float* ob = out + ((size_t)b * CIN + q4 * 4) * N + m0 + hm * 16 + l15;
#pragma unroll
      for (int r = 0; r < 4; ++r) atomicAdd(ob + (size_t)r * N, po[r]);
    }
  }
}

extern "C" void kernel_launch(void* const* d_in, const int* in_sizes, int n_in,
                              void* d_out, int out_size, void* d_ws, size_t ws_size,
                              hipStream_t stream) {
  const float* x  = (const float*)d_in[0];
  const float* wq = (const float*)d_in[1];
  const float* bq = (const float*)d_in[2];
  const float* wk = (const float*)d_in[3];
  const float* bk = (const float*)d_in[4];
  const float* wv = (const float*)d_in[5];
  const float* bv = (const float*)d_in[6];
  const float* wo = (const float*)d_in[7];
  const float* bo = (const float*)d_in[8];
  float* out = (float*)d_out;

  char* ws = (char*)d_ws;
  unsigned short* qT  = (unsigned short*)ws;                        // 3,145,728 B
  unsigned short* kT  = (unsigned short*)(ws + 3145728);            // 3,145,728 B
  unsigned short* vbf = (unsigned short*)(ws + 2 * 3145728);        // 3,145,728 B
  float* v    = (float*)(ws + 3 * 3145728);                         // 4,718,592 B
  float* psum = (float*)(ws + 3 * 3145728 + 4718592);               //   524,288 B

  qkv_kernel<<<dim3(B * N / 256, 3), 256, 0, stream>>>(x, wq, bq, wk, bk, wv, bv,
                                                       qT, kT, v);
  stats_kernel<<<dim3(N / 32, B, MSPLIT), 256, 0, stream>>>(qT, kT, psum);
  vscale_kernel<<<dim3(B * N / 256, 3), 256, 0, stream>>>(v, psum, vbf);
  init_kernel<<<B * CIN * N / 1024, 256, 0, stream>>>(out, bo);
  attn_kernel<<<dim3(N / 128, B, ZSPLIT), 256, 0, stream>>>(qT, kT, vbf, wo, out);
}

// Round 7
// 151.434 us; speedup vs baseline: 2.2033x; 1.1310x over previous
//
#include <hip/hip_runtime.h>
#include <hip/hip_bf16.h>
#include <math.h>

#define B 8
#define CIN 12
#define CQ 36
#define CP 48               // channel dim padded: 36 data + 2 logL + 10 zero
#define N 4096
#define SCALE 0.28867513459481287f   // 1/sqrt(12)
#define LOG2E 1.4426950408889634f
#define ZSPLIT 8
#define NCHUNK (N / ZSPLIT) // 512
#define NT (NCHUNK / 32)    // 16 tiles per attn WG
#define MSPLIT 4

typedef __attribute__((ext_vector_type(4)))  short bf4_t;
typedef __attribute__((ext_vector_type(8)))  short bf8_t;
typedef __attribute__((ext_vector_type(16))) float f32x16;
typedef __attribute__((ext_vector_type(4)))  float f32x4;

__device__ __forceinline__ unsigned short f2bf(float x) {
  unsigned int u = __float_as_uint(x);
  u += 0x7FFFu + ((u >> 16) & 1u);   // RNE
  return (unsigned short)(u >> 16);
}

#if __has_builtin(__builtin_amdgcn_cvt_pk_bf16_f32)
typedef __attribute__((ext_vector_type(2))) __bf16 bf16x2_t;
__device__ __forceinline__ unsigned pk2bf(float a, float b) {
  bf16x2_t v = __builtin_amdgcn_cvt_pk_bf16_f32(a, b);
  return __builtin_bit_cast(unsigned, v);
}
#else
__device__ __forceinline__ unsigned pk2bf(float a, float b) {
  return (__float_as_uint(a) >> 16) | (__float_as_uint(b) & 0xFFFF0000u);
}
#endif

__device__ __forceinline__ float bf2f(unsigned short u) {
  return __uint_as_float((unsigned)u << 16);
}

__device__ __forceinline__ float exp2fast(float x) {
#if __has_builtin(__builtin_amdgcn_exp2f)
  return __builtin_amdgcn_exp2f(x);
#else
  return exp2f(x);
#endif
}

// 16x16x16 quad-K MFMA (verified R4-R6): A[m=l15][k=q4*4+i], B[k][n=l15],
// D col=l15 row=q4*4+r.
__device__ __forceinline__ f32x4 mfma16(bf4_t a, bf4_t b, f32x4 c) {
#if __has_builtin(__builtin_amdgcn_mfma_f32_16x16x16bf16_1k)
  return __builtin_amdgcn_mfma_f32_16x16x16bf16_1k(a, b, c, 0, 0, 0);
#else
  bf8_t a8 = {a[0], a[1], a[2], a[3], 0, 0, 0, 0};
  bf8_t b8 = {b[0], b[1], b[2], b[3], 0, 0, 0, 0};
  return __builtin_amdgcn_mfma_f32_16x16x32_bf16(a8, b8, c, 0, 0, 0);
#endif
}

// 16B LDS access helpers for 8B-aligned addresses (rows padded to 104/72 B)
__device__ __forceinline__ bf8_t lds_bf8(const unsigned short* p) {
  uint2 a = *(const uint2*)p;
  uint2 b = *(const uint2*)(p + 4);
  uint4 r{a.x, a.y, b.x, b.y};
  return __builtin_bit_cast(bf8_t, r);
}
__device__ __forceinline__ void wlds16(unsigned short* p, uint4 v) {
  *(uint2*)p = uint2{v.x, v.y};
  *(uint2*)(p + 4) = uint2{v.z, v.w};
}

// ---------------- QKV projection: y-split over {q,k,v} ---------------------
// k scaled by SCALE*LOG2E (log2-domain scores). q ch36/37 = 1.0 (logL slot).
__global__ __launch_bounds__(256) void qkv_kernel(
    const float* __restrict__ x,
    const float* __restrict__ wq, const float* __restrict__ bq,
    const float* __restrict__ wk, const float* __restrict__ bk,
    const float* __restrict__ wv, const float* __restrict__ bv,
    unsigned short* __restrict__ qT, unsigned short* __restrict__ kT,
    unsigned short* __restrict__ vbf) {
  __shared__ float sw[CQ * CIN];
  __shared__ float sb[CQ];
  int z = blockIdx.y;   // 0->q, 1->k (scaled), 2->v
  const float* w  = (z == 0) ? wq : (z == 1) ? wk : wv;
  const float* bb = (z == 0) ? bq : (z == 1) ? bk : bv;
  float scale = (z == 1) ? SCALE * LOG2E : 1.0f;
  int tid = threadIdx.x;
  for (int e = tid; e < CQ * CIN; e += 256) sw[e] = w[e] * scale;
  if (tid < CQ) sb[tid] = bb[tid] * scale;
  __syncthreads();
  int gid = blockIdx.x * 256 + tid;    // over B*N
  int b = gid >> 12;
  int n = gid & (N - 1);
  float xv[CIN];
#pragma unroll
  for (int i = 0; i < CIN; ++i) xv[i] = x[(b * CIN + i) * N + n];
  if (z == 2) {
#pragma unroll
    for (int o = 0; o < CQ; ++o) {
      float a = sb[o];
#pragma unroll
      for (int i = 0; i < CIN; ++i) a += sw[o * CIN + i] * xv[i];
      vbf[((size_t)b * CP + o) * N + n] = f2bf(a);
    }
  } else {
    __attribute__((aligned(16))) unsigned row[CP / 2];
#pragma unroll
    for (int o = 0; o < CQ; o += 2) {
      float a0 = sb[o], a1 = sb[o + 1];
#pragma unroll
      for (int i = 0; i < CIN; ++i) {
        float xi = xv[i];
        a0 += sw[o * CIN + i] * xi;
        a1 += sw[(o + 1) * CIN + i] * xi;
      }
      row[o / 2] = (unsigned)f2bf(a0) | ((unsigned)f2bf(a1) << 16);
    }
    row[18] = (z == 0) ? 0x3F803F80u : 0u;  // q: ch36/37 = 1.0; k: 0 (finalize fills)
#pragma unroll
    for (int o = 19; o < CP / 2; ++o) row[o] = 0;
    unsigned short* dst = ((z == 0) ? qT : kT) + ((size_t)b * N + n) * CP;
#pragma unroll
    for (int i = 0; i < 6; ++i) *(uint4*)(dst + 8 * i) = *(const uint4*)&row[4 * i];
  }
}

// ---------------- Pass 1: psum[ms][b][n] = partial sum_m 2^(s[n,m]) --------
__global__ __launch_bounds__(256) void stats_kernel(
    const unsigned short* __restrict__ qT, const unsigned short* __restrict__ kT,
    float* __restrict__ psum) {
  __shared__ float red[4][32];
  int tid = threadIdx.x, lane = tid & 63, wave = tid >> 6;
  int b = blockIdx.y, nblk = blockIdx.x, ms = blockIdx.z;
  int l31 = lane & 31, h = lane >> 5;
  const unsigned short* krow = kT + ((size_t)b * N + nblk * 32 + l31) * CP + h * 8;
  bf8_t a0 = *(const bf8_t*)(krow);
  bf8_t a1 = *(const bf8_t*)(krow + 16);
  bf8_t a2 = *(const bf8_t*)(krow + 32);
  float rs[16];
#pragma unroll
  for (int r = 0; r < 16; ++r) rs[r] = 0.f;
  const int MW = N / MSPLIT / 4;   // 256 m per wave
  const unsigned short* qbase =
      qT + ((size_t)b * N + ms * (N / MSPLIT) + wave * MW + l31) * CP + h * 8;
#pragma unroll 2
  for (int t = 0; t < MW / 32; ++t) {
    const unsigned short* qrow2 = qbase + (size_t)t * 32 * CP;
    bf8_t b0 = *(const bf8_t*)(qrow2);
    bf8_t b1 = *(const bf8_t*)(qrow2 + 16);
    bf8_t b2 = *(const bf8_t*)(qrow2 + 32);
    f32x16 S;
#pragma unroll
    for (int r = 0; r < 16; ++r) S[r] = 0.f;
    S = __builtin_amdgcn_mfma_f32_32x32x16_bf16(a0, b0, S, 0, 0, 0);
    S = __builtin_amdgcn_mfma_f32_32x32x16_bf16(a1, b1, S, 0, 0, 0);
    S = __builtin_amdgcn_mfma_f32_32x32x16_bf16(a2, b2, S, 0, 0, 0);
#pragma unroll
    for (int r = 0; r < 16; ++r) rs[r] += exp2fast(S[r]);
  }
#pragma unroll
  for (int off = 16; off >= 1; off >>= 1)
#pragma unroll
    for (int r = 0; r < 16; ++r) rs[r] += __shfl_xor(rs[r], off, 32);
  if (l31 == 0) {
#pragma unroll
    for (int r = 0; r < 16; ++r) {
      int row = (r & 3) + 8 * (r >> 2) + 4 * h;   // 32x32 C/D row map
      red[wave][row] = rs[r];
    }
  }
  __syncthreads();
  if (tid < 32) {
    float s = red[0][tid] + red[1][tid] + red[2][tid] + red[3][tid];
    psum[((size_t)ms * B + b) * N + nblk * 32 + tid] = s;
  }
}

// ---------------- finalize: kT ch36/37 = hi/lo split of -log2(L_n) ---------
__global__ __launch_bounds__(256) void finalize_kernel(
    const float* __restrict__ psum, unsigned short* __restrict__ kT) {
  int gid = blockIdx.x * 256 + threadIdx.x;   // = b*N + n
  float L = 0.f;
#pragma unroll
  for (int ms = 0; ms < MSPLIT; ++ms) L += psum[(size_t)ms * B * N + gid];
  float t = -__log2f(L);
  unsigned short hi = f2bf(t);
  unsigned short lo = f2bf(t - bf2f(hi));
  size_t base = (size_t)gid * CP;
  kT[base + 36] = hi;
  kT[base + 37] = lo;
}

// ---------------- init out with bias (atomically accumulated) --------------
__global__ __launch_bounds__(256) void init_kernel(
    float* __restrict__ out, const float* __restrict__ bo) {
  int gid = blockIdx.x * 256 + threadIdx.x;   // over B*CIN*N/4
  int e4 = gid * 4;
  int i = (e4 >> 12) % CIN;
  float bv = bo[i];
  *(float4*)(out + e4) = float4{bv, bv, bv, bv};
}

// ---------------- Pass 2: cooperative-staged attn + fused projection -------
__global__ __launch_bounds__(256, 5) void attn_kernel(
    const unsigned short* __restrict__ qT, const unsigned short* __restrict__ kT,
    const unsigned short* __restrict__ vbf, const float* __restrict__ wo,
    float* __restrict__ out) {
  __shared__ unsigned short kbuf[2][32 * 52];   // [n][48+pad4], 104 B rows
  __shared__ unsigned short vbuf[2][48 * 36];   // [c][32+pad4], 72 B rows
  __shared__ unsigned short plds[4][32 * 40];   // per-wave P^T [m][n pad40]
  int tid = threadIdx.x, lane = tid & 63, wave = tid >> 6;
  int b = blockIdx.y, z = blockIdx.z, mblk = blockIdx.x;
  int l31 = lane & 31, h = lane >> 5, l15 = lane & 15, q4 = lane >> 4;
  int m0 = mblk * 128 + wave * 32;
  size_t bN = (size_t)b * N;
  // staging descriptors: 192 uint4 of k-tile + 192 uint4 of v-tile per tile
  bool isK0 = tid < 192;
  int r0row = isK0 ? (tid / 6) : ((tid - 192) >> 2);
  int r0c   = isK0 ? (tid % 6) : ((tid - 192) & 3);
  const unsigned short* s0 = isK0
      ? kT + (bN + z * NCHUNK + r0row) * CP + r0c * 8
      : vbf + ((size_t)b * CP + r0row) * N + z * NCHUNK + r0c * 8;
  int s0stride = isK0 ? 32 * CP : 32;
  unsigned short* dst0 = isK0 ? &kbuf[0][r0row * 52 + r0c * 8]
                              : &vbuf[0][r0row * 36 + r0c * 8];
  int dbs0 = isK0 ? 32 * 52 : 48 * 36;
  bool has1 = tid < 128;                      // second item: v rows 16..47
  int r1row = (tid >> 2) + 16;
  int r1c = tid & 3;
  const unsigned short* s1 =
      vbf + ((size_t)b * CP + r1row) * N + z * NCHUNK + r1c * 8;
  unsigned short* dst1 = &vbuf[0][r1row * 36 + r1c * 8];
  const int dbs1 = 48 * 36;
  // q B-frags (loop-invariant), incl ch36/37 = 1.0
  const unsigned short* qrow = qT + (bN + m0 + l31) * CP + h * 8;
  bf8_t qb0 = *(const bf8_t*)(qrow);
  bf8_t qb1 = *(const bf8_t*)(qrow + 16);
  bf8_t qb2 = *(const bf8_t*)(qrow + 32);
  // wo A-frags: A[i=l15][k=16ct+q4*4+j], zero outside 12x36
  bf4_t woa[3];
#pragma unroll
  for (int ct = 0; ct < 3; ++ct) {
    float4 w4 = {0.f, 0.f, 0.f, 0.f};
    int col = 16 * ct + q4 * 4;
    if (l15 < CIN && col < CQ) w4 = *(const float4*)(wo + l15 * CQ + col);
    woa[ct] = bf4_t{(short)f2bf(w4.x), (short)f2bf(w4.y),
                    (short)f2bf(w4.z), (short)f2bf(w4.w)};
  }
  f32x4 acc[3][2];
#pragma unroll
  for (int ct = 0; ct < 3; ++ct)
#pragma unroll
    for (int hm = 0; hm < 2; ++hm)
#pragma unroll
      for (int r = 0; r < 4; ++r) acc[ct][hm][r] = 0.f;
  unsigned short* pl = plds[wave];
  // prologue: stage tile 0
  uint4 r0 = *(const uint4*)s0; s0 += s0stride;
  uint4 r1{0, 0, 0, 0};
  if (has1) { r1 = *(const uint4*)s1; s1 += 32; }
  wlds16(dst0, r0);
  if (has1) wlds16(dst1, r1);
  __syncthreads();
  for (int t = 0; t < NT; ++t) {
    int buf = t & 1;
    if (t + 1 < NT) {                       // prefetch next tile into regs
      r0 = *(const uint4*)s0; s0 += s0stride;
      if (has1) { r1 = *(const uint4*)s1; s1 += 32; }
    }
    const unsigned short* kb = kbuf[buf];
    const unsigned short* vb = vbuf[buf];
    bf8_t a0 = lds_bf8(kb + l31 * 52 + h * 8);
    bf8_t a1 = lds_bf8(kb + l31 * 52 + h * 8 + 16);
    bf8_t a2 = lds_bf8(kb + l31 * 52 + h * 8 + 32);
    f32x16 S;
#pragma unroll
    for (int r = 0; r < 16; ++r) S[r] = 0.f;
    S = __builtin_amdgcn_mfma_f32_32x32x16_bf16(a0, qb0, S, 0, 0, 0);
    S = __builtin_amdgcn_mfma_f32_32x32x16_bf16(a1, qb1, S, 0, 0, 0);
    S = __builtin_amdgcn_mfma_f32_32x32x16_bf16(a2, qb2, S, 0, 0, 0);
    // P = 2^(s - log2 L) already normalized; transpose-store per-wave
#pragma unroll
    for (int qd = 0; qd < 4; ++qd) {
      uint2 pk;
      pk.x = pk2bf(exp2fast(S[4 * qd + 0]), exp2fast(S[4 * qd + 1]));
      pk.y = pk2bf(exp2fast(S[4 * qd + 2]), exp2fast(S[4 * qd + 3]));
      *(uint2*)&pl[l31 * 40 + 8 * qd + 4 * h] = pk;
    }
    bf8_t pb0 = *(const bf8_t*)&pl[l15 * 40 + q4 * 8];
    bf8_t pb1 = *(const bf8_t*)&pl[(16 + l15) * 40 + q4 * 8];
    bf8_t v0 = lds_bf8(vb + (0 * 16 + l15) * 36 + q4 * 8);
    bf8_t v1 = lds_bf8(vb + (1 * 16 + l15) * 36 + q4 * 8);
    bf8_t v2 = lds_bf8(vb + (2 * 16 + l15) * 36 + q4 * 8);
    acc[0][0] = __builtin_amdgcn_mfma_f32_16x16x32_bf16(v0, pb0, acc[0][0], 0, 0, 0);
    acc[0][1] = __builtin_amdgcn_mfma_f32_16x16x32_bf16(v0, pb1, acc[0][1], 0, 0, 0);
    acc[1][0] = __builtin_amdgcn_mfma_f32_16x16x32_bf16(v1, pb0, acc[1][0], 0, 0, 0);
    acc[1][1] = __builtin_amdgcn_mfma_f32_16x16x32_bf16(v1, pb1, acc[1][1], 0, 0, 0);
    acc[2][0] = __builtin_amdgcn_mfma_f32_16x16x32_bf16(v2, pb0, acc[2][0], 0, 0, 0);
    acc[2][1] = __builtin_amdgcn_mfma_f32_16x16x32_bf16(v2, pb1, acc[2][1], 0, 0, 0);
    if (t + 1 < NT) {                       // stage next tile into other buf
      int nb = buf ^ 1;
      wlds16(dst0 + nb * dbs0, r0);
      if (has1) wlds16(dst1 + nb * dbs1, r1);
    }
    __syncthreads();
  }
  // fused projection: acc tile (C-layout) == quad-K B-operand layout
#pragma unroll
  for (int hm = 0; hm < 2; ++hm) {
    f32x4 po = {0.f, 0.f, 0.f, 0.f};
#pragma unroll
    for (int ct = 0; ct < 3; ++ct) {
      union { uint2 u; bf4_t v; } pb;
      pb.u.x = pk2bf(acc[ct][hm][0], acc[ct][hm][1]);
      pb.u.y = pk2bf(acc[ct][hm][2], acc[ct][hm][3]);
      po = mfma16(woa[ct], pb.v, po);
    }
    if (q4 < 3) {
      float* ob = out + ((size_t)b * CIN + q4 * 4) * N + m0 + hm * 16 + l15;
#pragma unroll
      for (int r = 0; r < 4; ++r) atomicAdd(ob + (size_t)r * N, po[r]);
    }
  }
}

extern "C" void kernel_launch(void* const* d_in, const int* in_sizes, int n_in,
                              void* d_out, int out_size, void* d_ws, size_t ws_size,
                              hipStream_t stream) {
  const float* x  = (const float*)d_in[0];
  const float* wq = (const float*)d_in[1];
  const float* bq = (const float*)d_in[2];
  const float* wk = (const float*)d_in[3];
  const float* bk = (const float*)d_in[4];
  const float* wv = (const float*)d_in[5];
  const float* bv = (const float*)d_in[6];
  const float* wo = (const float*)d_in[7];
  const float* bo = (const float*)d_in[8];
  float* out = (float*)d_out;

  char* ws = (char*)d_ws;
  unsigned short* qT  = (unsigned short*)ws;                 // 3,145,728 B
  unsigned short* kT  = (unsigned short*)(ws + 3145728);     // 3,145,728 B
  unsigned short* vbf = (unsigned short*)(ws + 2 * 3145728); // 3,145,728 B
  float* psum = (float*)(ws + 3 * 3145728);                  //   524,288 B

  qkv_kernel<<<dim3(B * N / 256, 3), 256, 0, stream>>>(x, wq, bq, wk, bk, wv, bv,
                                                       qT, kT, vbf);
  stats_kernel<<<dim3(N / 32, B, MSPLIT), 256, 0, stream>>>(qT, kT, psum);
  finalize_kernel<<<B * N / 256, 256, 0, stream>>>(psum, kT);
  init_kernel<<<B * CIN * N / 1024, 256, 0, stream>>>(out, bo);
  attn_kernel<<<dim3(N / 128, B, ZSPLIT), 256, 0, stream>>>(qT, kT, vbf, wo, out);
}

// Round 8
// 135.857 us; speedup vs baseline: 2.4559x; 1.1147x over previous
//
#include <hip/hip_runtime.h>
#include <hip/hip_bf16.h>
#include <math.h>

#define B 8
#define CIN 12
#define CQ 36
#define CP 48               // channel dim padded: 36 data + 2 logL + 10 zero
#define N 4096
#define SCALE 0.28867513459481287f   // 1/sqrt(12)
#define LOG2E 1.4426950408889634f
#define ZSPLIT 8
#define NCHUNK (N / ZSPLIT) // 512
#define NT (NCHUNK / 32)    // 16 tiles per attn WG
#define MSPLIT 2

typedef __attribute__((ext_vector_type(4)))  short bf4_t;
typedef __attribute__((ext_vector_type(8)))  short bf8_t;
typedef __attribute__((ext_vector_type(16))) float f32x16;
typedef __attribute__((ext_vector_type(4)))  float f32x4;

__device__ __forceinline__ unsigned short f2bf(float x) {
  unsigned int u = __float_as_uint(x);
  u += 0x7FFFu + ((u >> 16) & 1u);   // RNE
  return (unsigned short)(u >> 16);
}

#if __has_builtin(__builtin_amdgcn_cvt_pk_bf16_f32)
typedef __attribute__((ext_vector_type(2))) __bf16 bf16x2_t;
__device__ __forceinline__ unsigned pk2bf(float a, float b) {
  bf16x2_t v = __builtin_amdgcn_cvt_pk_bf16_f32(a, b);
  return __builtin_bit_cast(unsigned, v);
}
#else
__device__ __forceinline__ unsigned pk2bf(float a, float b) {
  return (__float_as_uint(a) >> 16) | (__float_as_uint(b) & 0xFFFF0000u);
}
#endif

__device__ __forceinline__ float bf2f(unsigned short u) {
  return __uint_as_float((unsigned)u << 16);
}

__device__ __forceinline__ float exp2fast(float x) {
#if __has_builtin(__builtin_amdgcn_exp2f)
  return __builtin_amdgcn_exp2f(x);
#else
  return exp2f(x);
#endif
}

// 16x16x16 quad-K MFMA (verified R4-R7): A[m=l15][k=q4*4+i], B[k][n=l15],
// D col=l15 row=q4*4+r.
__device__ __forceinline__ f32x4 mfma16(bf4_t a, bf4_t b, f32x4 c) {
#if __has_builtin(__builtin_amdgcn_mfma_f32_16x16x16bf16_1k)
  return __builtin_amdgcn_mfma_f32_16x16x16bf16_1k(a, b, c, 0, 0, 0);
#else
  bf8_t a8 = {a[0], a[1], a[2], a[3], 0, 0, 0, 0};
  bf8_t b8 = {b[0], b[1], b[2], b[3], 0, 0, 0, 0};
  return __builtin_amdgcn_mfma_f32_16x16x32_bf16(a8, b8, c, 0, 0, 0);
#endif
}

// 16B LDS access helpers for 8B-aligned addresses (rows padded to 104/72 B)
__device__ __forceinline__ bf8_t lds_bf8(const unsigned short* p) {
  uint2 a = *(const uint2*)p;
  uint2 b = *(const uint2*)(p + 4);
  uint4 r{a.x, a.y, b.x, b.y};
  return __builtin_bit_cast(bf8_t, r);
}
__device__ __forceinline__ void wlds16(unsigned short* p, uint4 v) {
  *(uint2*)p = uint2{v.x, v.y};
  *(uint2*)(p + 4) = uint2{v.z, v.w};
}

// ---------------- QKV projection: y-split over {q,k,v} ---------------------
__global__ __launch_bounds__(256) void qkv_kernel(
    const float* __restrict__ x,
    const float* __restrict__ wq, const float* __restrict__ bq,
    const float* __restrict__ wk, const float* __restrict__ bk,
    const float* __restrict__ wv, const float* __restrict__ bv,
    unsigned short* __restrict__ qT, unsigned short* __restrict__ kT,
    unsigned short* __restrict__ vbf) {
  __shared__ float sw[CQ * CIN];
  __shared__ float sb[CQ];
  int z = blockIdx.y;   // 0->q, 1->k (scaled), 2->v
  const float* w  = (z == 0) ? wq : (z == 1) ? wk : wv;
  const float* bb = (z == 0) ? bq : (z == 1) ? bk : bv;
  float scale = (z == 1) ? SCALE * LOG2E : 1.0f;
  int tid = threadIdx.x;
  for (int e = tid; e < CQ * CIN; e += 256) sw[e] = w[e] * scale;
  if (tid < CQ) sb[tid] = bb[tid] * scale;
  __syncthreads();
  int gid = blockIdx.x * 256 + tid;    // over B*N
  int b = gid >> 12;
  int n = gid & (N - 1);
  float xv[CIN];
#pragma unroll
  for (int i = 0; i < CIN; ++i) xv[i] = x[(b * CIN + i) * N + n];
  if (z == 2) {
#pragma unroll
    for (int o = 0; o < CQ; ++o) {
      float a = sb[o];
#pragma unroll
      for (int i = 0; i < CIN; ++i) a += sw[o * CIN + i] * xv[i];
      vbf[((size_t)b * CP + o) * N + n] = f2bf(a);
    }
  } else {
    __attribute__((aligned(16))) unsigned row[CP / 2];
#pragma unroll
    for (int o = 0; o < CQ; o += 2) {
      float a0 = sb[o], a1 = sb[o + 1];
#pragma unroll
      for (int i = 0; i < CIN; ++i) {
        float xi = xv[i];
        a0 += sw[o * CIN + i] * xi;
        a1 += sw[(o + 1) * CIN + i] * xi;
      }
      row[o / 2] = (unsigned)f2bf(a0) | ((unsigned)f2bf(a1) << 16);
    }
    row[18] = (z == 0) ? 0x3F803F80u : 0u;  // q: ch36/37=1.0; k: filled by prep
#pragma unroll
    for (int o = 19; o < CP / 2; ++o) row[o] = 0;
    unsigned short* dst = ((z == 0) ? qT : kT) + ((size_t)b * N + n) * CP;
#pragma unroll
    for (int i = 0; i < 6; ++i) *(uint4*)(dst + 8 * i) = *(const uint4*)&row[4 * i];
  }
}

// ---------------- Pass 1: psum[ms][b][n], 2 n-blocks per wave --------------
__global__ __launch_bounds__(256) void stats_kernel(
    const unsigned short* __restrict__ qT, const unsigned short* __restrict__ kT,
    float* __restrict__ psum) {
  __shared__ float red[4][64];
  int tid = threadIdx.x, lane = tid & 63, wave = tid >> 6;
  int b = blockIdx.y, nblk = blockIdx.x, ms = blockIdx.z;
  int l31 = lane & 31, h = lane >> 5;
  int n0 = nblk * 64;
  size_t bN = (size_t)b * N;
  const unsigned short* krow0 = kT + (bN + n0 + l31) * CP + h * 8;
  const unsigned short* krow1 = krow0 + (size_t)32 * CP;
  bf8_t a0 = *(const bf8_t*)(krow0);
  bf8_t a1 = *(const bf8_t*)(krow0 + 16);
  bf8_t a2 = *(const bf8_t*)(krow0 + 32);
  bf8_t a3 = *(const bf8_t*)(krow1);
  bf8_t a4 = *(const bf8_t*)(krow1 + 16);
  bf8_t a5 = *(const bf8_t*)(krow1 + 32);
  float rs0[16], rs1[16];
#pragma unroll
  for (int r = 0; r < 16; ++r) { rs0[r] = 0.f; rs1[r] = 0.f; }
  const int MW = N / MSPLIT / 4;   // 512 m per wave
  const unsigned short* qbase =
      qT + (bN + ms * (N / MSPLIT) + wave * MW + l31) * CP + h * 8;
#pragma unroll 2
  for (int t = 0; t < MW / 32; ++t) {
    const unsigned short* qrow2 = qbase + (size_t)t * 32 * CP;
    bf8_t b0 = *(const bf8_t*)(qrow2);
    bf8_t b1 = *(const bf8_t*)(qrow2 + 16);
    bf8_t b2 = *(const bf8_t*)(qrow2 + 32);
    f32x16 S0, S1;
#pragma unroll
    for (int r = 0; r < 16; ++r) { S0[r] = 0.f; S1[r] = 0.f; }
    S0 = __builtin_amdgcn_mfma_f32_32x32x16_bf16(a0, b0, S0, 0, 0, 0);
    S0 = __builtin_amdgcn_mfma_f32_32x32x16_bf16(a1, b1, S0, 0, 0, 0);
    S0 = __builtin_amdgcn_mfma_f32_32x32x16_bf16(a2, b2, S0, 0, 0, 0);
    S1 = __builtin_amdgcn_mfma_f32_32x32x16_bf16(a3, b0, S1, 0, 0, 0);
    S1 = __builtin_amdgcn_mfma_f32_32x32x16_bf16(a4, b1, S1, 0, 0, 0);
    S1 = __builtin_amdgcn_mfma_f32_32x32x16_bf16(a5, b2, S1, 0, 0, 0);
#pragma unroll
    for (int r = 0; r < 16; ++r) {
      rs0[r] += exp2fast(S0[r]);
      rs1[r] += exp2fast(S1[r]);
    }
  }
#pragma unroll
  for (int off = 16; off >= 1; off >>= 1)
#pragma unroll
    for (int r = 0; r < 16; ++r) {
      rs0[r] += __shfl_xor(rs0[r], off, 32);
      rs1[r] += __shfl_xor(rs1[r], off, 32);
    }
  if (l31 == 0) {
#pragma unroll
    for (int r = 0; r < 16; ++r) {
      int row = (r & 3) + 8 * (r >> 2) + 4 * h;   // 32x32 C/D row map
      red[wave][row] = rs0[r];
      red[wave][32 + row] = rs1[r];
    }
  }
  __syncthreads();
  if (tid < 64) {
    float s = red[0][tid] + red[1][tid] + red[2][tid] + red[3][tid];
    psum[((size_t)ms * B + b) * N + n0 + tid] = s;
  }
}

// ---------------- prep: finalize logL into kT  +  init out with bias -------
__global__ __launch_bounds__(256) void prep_kernel(
    const float* __restrict__ psum, unsigned short* __restrict__ kT,
    float* __restrict__ out, const float* __restrict__ bo) {
  int bx = blockIdx.x, tid = threadIdx.x;
  if (bx < B * N / 256) {
    int gid = bx * 256 + tid;   // = b*N + n
    float L = 0.f;
#pragma unroll
    for (int ms = 0; ms < MSPLIT; ++ms) L += psum[(size_t)ms * B * N + gid];
    float t = -__log2f(L);
    unsigned short hi = f2bf(t);
    unsigned short lo = f2bf(t - bf2f(hi));
    size_t base = (size_t)gid * CP;
    kT[base + 36] = hi;
    kT[base + 37] = lo;
  } else {
    int gid = (bx - B * N / 256) * 256 + tid;   // over B*CIN*N/4
    int e4 = gid * 4;
    int i = (e4 >> 12) % CIN;
    float bv = bo[i];
    *(float4*)(out + e4) = float4{bv, bv, bv, bv};
  }
}

// ---------------- Pass 2: staged attn, 2 m-tiles/wave, fused projection ----
__global__ __launch_bounds__(256, 3) void attn_kernel(
    const unsigned short* __restrict__ qT, const unsigned short* __restrict__ kT,
    const unsigned short* __restrict__ vbf, const float* __restrict__ wo,
    float* __restrict__ out) {
  __shared__ unsigned short kbuf[2][32 * 52];     // [n][48+pad4], 104 B rows
  __shared__ unsigned short vbuf[2][48 * 36];     // [c][32+pad4], 72 B rows
  __shared__ unsigned short plds[4][2][32 * 40];  // per-wave 2x P^T [m][n pad40]
  int tid = threadIdx.x, lane = tid & 63, wave = tid >> 6;
  int b = blockIdx.y, z = blockIdx.z, mblk = blockIdx.x;
  int l31 = lane & 31, h = lane >> 5, l15 = lane & 15, q4 = lane >> 4;
  int m0 = mblk * 256 + wave * 64;
  size_t bN = (size_t)b * N;
  // staging: 192 uint4 k-tile + 192 uint4 v-tile per 32-n tile
  bool isK0 = tid < 192;
  int r0row = isK0 ? (tid / 6) : ((tid - 192) >> 2);
  int r0c   = isK0 ? (tid % 6) : ((tid - 192) & 3);
  const unsigned short* s0 = isK0
      ? kT + (bN + z * NCHUNK + r0row) * CP + r0c * 8
      : vbf + ((size_t)b * CP + r0row) * N + z * NCHUNK + r0c * 8;
  int s0stride = isK0 ? 32 * CP : 32;
  unsigned short* dst0 = isK0 ? &kbuf[0][r0row * 52 + r0c * 8]
                              : &vbuf[0][r0row * 36 + r0c * 8];
  int dbs0 = isK0 ? 32 * 52 : 48 * 36;
  bool has1 = tid < 128;                      // second item: v rows 16..47
  int r1row = (tid >> 2) + 16;
  int r1c = tid & 3;
  const unsigned short* s1 =
      vbf + ((size_t)b * CP + r1row) * N + z * NCHUNK + r1c * 8;
  unsigned short* dst1 = &vbuf[0][r1row * 36 + r1c * 8];
  const int dbs1 = 48 * 36;
  // q B-frags for two m-tiles (loop-invariant), incl ch36/37 = 1.0
  bf8_t qb[2][3];
#pragma unroll
  for (int mt = 0; mt < 2; ++mt) {
    const unsigned short* qrow = qT + (bN + m0 + mt * 32 + l31) * CP + h * 8;
    qb[mt][0] = *(const bf8_t*)(qrow);
    qb[mt][1] = *(const bf8_t*)(qrow + 16);
    qb[mt][2] = *(const bf8_t*)(qrow + 32);
  }
  // wo A-frags: A[i=l15][k=16ct+q4*4+j], zero outside 12x36
  bf4_t woa[3];
#pragma unroll
  for (int ct = 0; ct < 3; ++ct) {
    float4 w4 = {0.f, 0.f, 0.f, 0.f};
    int col = 16 * ct + q4 * 4;
    if (l15 < CIN && col < CQ) w4 = *(const float4*)(wo + l15 * CQ + col);
    woa[ct] = bf4_t{(short)f2bf(w4.x), (short)f2bf(w4.y),
                    (short)f2bf(w4.z), (short)f2bf(w4.w)};
  }
  f32x4 acc[2][3][2];
#pragma unroll
  for (int mt = 0; mt < 2; ++mt)
#pragma unroll
    for (int ct = 0; ct < 3; ++ct)
#pragma unroll
      for (int hm = 0; hm < 2; ++hm)
#pragma unroll
        for (int r = 0; r < 4; ++r) acc[mt][ct][hm][r] = 0.f;
  // prologue: stage tile 0
  uint4 r0 = *(const uint4*)s0; s0 += s0stride;
  uint4 r1{0, 0, 0, 0};
  if (has1) { r1 = *(const uint4*)s1; s1 += 32; }
  wlds16(dst0, r0);
  if (has1) wlds16(dst1, r1);
  __syncthreads();
  for (int t = 0; t < NT; ++t) {
    int buf = t & 1;
    if (t + 1 < NT) {                       // prefetch next tile into regs
      r0 = *(const uint4*)s0; s0 += s0stride;
      if (has1) { r1 = *(const uint4*)s1; s1 += 32; }
    }
    const unsigned short* kb = kbuf[buf];
    const unsigned short* vb = vbuf[buf];
    bf8_t a0 = lds_bf8(kb + l31 * 52 + h * 8);
    bf8_t a1 = lds_bf8(kb + l31 * 52 + h * 8 + 16);
    bf8_t a2 = lds_bf8(kb + l31 * 52 + h * 8 + 32);
    // two independent S -> exp -> pack chains
#pragma unroll
    for (int mt = 0; mt < 2; ++mt) {
      f32x16 S;
#pragma unroll
      for (int r = 0; r < 16; ++r) S[r] = 0.f;
      S = __builtin_amdgcn_mfma_f32_32x32x16_bf16(a0, qb[mt][0], S, 0, 0, 0);
      S = __builtin_amdgcn_mfma_f32_32x32x16_bf16(a1, qb[mt][1], S, 0, 0, 0);
      S = __builtin_amdgcn_mfma_f32_32x32x16_bf16(a2, qb[mt][2], S, 0, 0, 0);
      unsigned short* pl = plds[wave][mt];
#pragma unroll
      for (int qd = 0; qd < 4; ++qd) {
        uint2 pk;
        pk.x = pk2bf(exp2fast(S[4 * qd + 0]), exp2fast(S[4 * qd + 1]));
        pk.y = pk2bf(exp2fast(S[4 * qd + 2]), exp2fast(S[4 * qd + 3]));
        *(uint2*)&pl[l31 * 40 + 8 * qd + 4 * h] = pk;
      }
    }
    bf8_t v0 = lds_bf8(vb + (0 * 16 + l15) * 36 + q4 * 8);
    bf8_t v1 = lds_bf8(vb + (1 * 16 + l15) * 36 + q4 * 8);
    bf8_t v2 = lds_bf8(vb + (2 * 16 + l15) * 36 + q4 * 8);
#pragma unroll
    for (int mt = 0; mt < 2; ++mt) {
      const unsigned short* pl = plds[wave][mt];
      bf8_t pb0 = *(const bf8_t*)&pl[l15 * 40 + q4 * 8];
      bf8_t pb1 = *(const bf8_t*)&pl[(16 + l15) * 40 + q4 * 8];
      acc[mt][0][0] = __builtin_amdgcn_mfma_f32_16x16x32_bf16(v0, pb0, acc[mt][0][0], 0, 0, 0);
      acc[mt][0][1] = __builtin_amdgcn_mfma_f32_16x16x32_bf16(v0, pb1, acc[mt][0][1], 0, 0, 0);
      acc[mt][1][0] = __builtin_amdgcn_mfma_f32_16x16x32_bf16(v1, pb0, acc[mt][1][0], 0, 0, 0);
      acc[mt][1][1] = __builtin_amdgcn_mfma_f32_16x16x32_bf16(v1, pb1, acc[mt][1][1], 0, 0, 0);
      acc[mt][2][0] = __builtin_amdgcn_mfma_f32_16x16x32_bf16(v2, pb0, acc[mt][2][0], 0, 0, 0);
      acc[mt][2][1] = __builtin_amdgcn_mfma_f32_16x16x32_bf16(v2, pb1, acc[mt][2][1], 0, 0, 0);
    }
    if (t + 1 < NT) {                       // stage next tile into other buf
      int nb = buf ^ 1;
      wlds16(dst0 + nb * dbs0, r0);
      if (has1) wlds16(dst1 + nb * dbs1, r1);
    }
    __syncthreads();
  }
  // fused projection: acc tile (C-layout) == quad-K B-operand layout
#pragma unroll
  for (int mt = 0; mt < 2; ++mt)
#pragma unroll
    for (int hm = 0; hm < 2; ++hm) {
      f32x4 po = {0.f, 0.f, 0.f, 0.f};
#pragma unroll
      for (int ct = 0; ct < 3; ++ct) {
        union { uint2 u; bf4_t v; } pb;
        pb.u.x = pk2bf(acc[mt][ct][hm][0], acc[mt][ct][hm][1]);
        pb.u.y = pk2bf(acc[mt][ct][hm][2], acc[mt][ct][hm][3]);
        po = mfma16(woa[ct], pb.v, po);
      }
      if (q4 < 3) {
        float* ob = out + ((size_t)b * CIN + q4 * 4) * N + m0 + mt * 32 + hm * 16 + l15;
#pragma unroll
        for (int r = 0; r < 4; ++r) atomicAdd(ob + (size_t)r * N, po[r]);
      }
    }
}

extern "C" void kernel_launch(void* const* d_in, const int* in_sizes, int n_in,
                              void* d_out, int out_size, void* d_ws, size_t ws_size,
                              hipStream_t stream) {
  const float* x  = (const float*)d_in[0];
  const float* wq = (const float*)d_in[1];
  const float* bq = (const float*)d_in[2];
  const float* wk = (const float*)d_in[3];
  const float* bk = (const float*)d_in[4];
  const float* wv = (const float*)d_in[5];
  const float* bv = (const float*)d_in[6];
  const float* wo = (const float*)d_in[7];
  const float* bo = (const float*)d_in[8];
  float* out = (float*)d_out;

  char* ws = (char*)d_ws;
  unsigned short* qT  = (unsigned short*)ws;                 // 3,145,728 B
  unsigned short* kT  = (unsigned short*)(ws + 3145728);     // 3,145,728 B
  unsigned short* vbf = (unsigned short*)(ws + 2 * 3145728); // 3,145,728 B
  float* psum = (float*)(ws + 3 * 3145728);                  //   262,144 B

  qkv_kernel<<<dim3(B * N / 256, 3), 256, 0, stream>>>(x, wq, bq, wk, bk, wv, bv,
                                                       qT, kT, vbf);
  stats_kernel<<<dim3(N / 64, B, MSPLIT), 256, 0, stream>>>(qT, kT, psum);
  prep_kernel<<<B * N / 256 + B * CIN * N / 1024, 256, 0, stream>>>(psum, kT, out, bo);
  attn_kernel<<<dim3(N / 256, B, ZSPLIT), 256, 0, stream>>>(qT, kT, vbf, wo, out);
}